// Round 1
// baseline (569.504 us; speedup 1.0000x reference)
//
#include <hip/hip_runtime.h>
#include <math.h>

#define C_NUM 345
#define A_DIM 512
#define N_NUM 128
#define KB    64    // b-range (GEMM K) per block
#define NBB   8     // blocks along b

typedef short bf16x8 __attribute__((ext_vector_type(8)));
typedef float f32x4  __attribute__((ext_vector_type(4)));

__device__ __forceinline__ short f2bf(float f) {
    unsigned u = __builtin_bit_cast(unsigned, f);
    u += 0x7fffu + ((u >> 16) & 1u);   // RNE
    return (short)(u >> 16);
}

// XOR-swizzled LDS index (in shorts) for 128x64 bf16 tiles. Row stride is
// 64 shorts = 128 B = exactly one bank sweep, so equal-k column reads of 16
// consecutive rows would be 16-way conflicted; XOR-ing the 16B-chunk index
// with (row&7) spreads them to 2 lanes/slot (free).
__device__ __forceinline__ int swz64(int r, int k) {
    return r * 64 + ((((k >> 3) ^ (r & 7)) << 3) | (k & 7));
}

// q2buf[bb][n][c] = sum_{a} sum_{b in bb's range} v[c,a]*Sigma_l[a,b]*v[c,b],
// v = W - w_l.  MFMA: u[a,c] = sum_b Sigma[a,b]*v[c,b]; epilogue dots u with v
// over a (C/D layout: col=lane&15 -> c, row=g*4+reg -> 4 consecutive a).
// Only the FIRST occurrence of each label computes (q2 depends on l only);
// losskern gathers through rep(n).
__global__ __launch_bounds__(256, 2) void qkern(
    const float* __restrict__ W,      // [C, A]
    const int*   __restrict__ labels, // [N]
    const float* __restrict__ cov,    // [C, A, A]
    float*       __restrict__ q2buf)  // [NBB, N, C] plain stores (no memset)
{
    const int bb = blockIdx.x;        // 0..7  (b-range)
    const int n  = blockIdx.y;        // 0..127
    const int l  = labels[n];
    // dedup: ~107 of 128 n's survive; uniform branch, no barrier crossed
    for (int m = 0; m < n; m++) if (labels[m] == l) return;

    const int b0 = bb * KB;
    const float* __restrict__ Sg = cov + (size_t)l * A_DIM * A_DIM;
    const float* __restrict__ Wl = W + (size_t)l * A_DIM;

    __shared__ short Sa[128 * 64];     // Sigma rows a (at-chunk), k = b
    __shared__ short Vb[3][128 * 64];  // V rows c (all 3 chunks resident), k = b
    __shared__ float qred[384];        // cross-wave (wa) partial exchange

    const int tid  = threadIdx.x;
    const int lane = tid & 63;
    const int w    = tid >> 6;        // wave 0..3
    const int wa   = w & 1;           // a-half of 128-tile
    const int wc   = w >> 1;          // c-half of 128-tile
    const int l15  = lane & 15;
    const int g    = lane >> 4;       // 0..3

    // staging coords: 16 threads per 64-col row (float4 each), 16 rows/pass
    const int c4 = tid & 15;
    const int r0 = tid >> 4;

    const float4 wl4 = *(const float4*)(Wl + b0 + c4 * 4);

    // stage V ONCE: b-range fixed for this block, at-independent (was 4x before)
#pragma unroll
    for (int ch = 0; ch < 3; ch++)
#pragma unroll
        for (int p = 0; p < 8; p++) {
            const int r = r0 + p * 16;
            const int c = ch * 128 + r;
            short4 h;
            if (c < C_NUM) {
                const float4 wv = *(const float4*)(W + (size_t)c * A_DIM + b0 + c4 * 4);
                h = make_short4(f2bf(wv.x - wl4.x), f2bf(wv.y - wl4.y),
                                f2bf(wv.z - wl4.z), f2bf(wv.w - wl4.w));
            } else {
                h = make_short4(0, 0, 0, 0);
            }
            *(short4*)(&Vb[ch][swz64(r, c4 * 4)]) = h;
        }

    float qp[3][4];
#pragma unroll
    for (int ct = 0; ct < 3; ct++)
#pragma unroll
        for (int j = 0; j < 4; j++) qp[ct][j] = 0.f;

    for (int at = 0; at < A_DIM; at += 128) {
        __syncthreads();  // previous at's Sa readers done before overwrite
        // stage Sa: Sigma[at..at+128) x [b0..b0+64)  (HBM, the only big fetch)
#pragma unroll
        for (int p = 0; p < 8; p++) {
            const int r = r0 + p * 16;
            const float4 s = *(const float4*)(Sg + (size_t)(at + r) * A_DIM + b0 + c4 * 4);
            *(short4*)(&Sa[swz64(r, c4 * 4)]) =
                make_short4(f2bf(s.x), f2bf(s.y), f2bf(s.z), f2bf(s.w));
        }
        __syncthreads();  // Sa (and, at at==0, Vb) visible to MFMA readers

        // epilogue Wl float4s for this at (reused across ct)
        float4 wle[4];
#pragma unroll
        for (int i = 0; i < 4; i++)
            wle[i] = *(const float4*)(Wl + at + wa * 64 + i * 16 + g * 4);

#pragma unroll
        for (int ct = 0; ct < 3; ct++) {
            f32x4 acc[4][4];
#pragma unroll
            for (int i = 0; i < 4; i++)
#pragma unroll
                for (int j = 0; j < 4; j++) {
                    f32x4 z = {0.f, 0.f, 0.f, 0.f};
                    acc[i][j] = z;
                }

#pragma unroll
            for (int kt = 0; kt < 2; kt++) {
                const int kbase = kt * 32 + g * 8;   // A/B frag: k = quad*8+j
                bf16x8 af[4], bfr[4];
#pragma unroll
                for (int i = 0; i < 4; i++)
                    af[i] = *(const bf16x8*)(&Sa[swz64(wa * 64 + i * 16 + l15, kbase)]);
#pragma unroll
                for (int j = 0; j < 4; j++)
                    bfr[j] = *(const bf16x8*)(&Vb[ct][swz64(wc * 64 + j * 16 + l15, kbase)]);
#pragma unroll
                for (int i = 0; i < 4; i++)
#pragma unroll
                    for (int j = 0; j < 4; j++)
                        acc[i][j] = __builtin_amdgcn_mfma_f32_16x16x32_bf16(
                            af[i], bfr[j], acc[i][j], 0, 0, 0);
            }

            // epilogue: qp[ct][j] += sum over this at of u[a,c]*v[c,a]
#pragma unroll
            for (int i = 0; i < 4; i++) {
                const int a0 = at + wa * 64 + i * 16 + g * 4;
                const float4 wl_e = wle[i];
#pragma unroll
                for (int j = 0; j < 4; j++) {
                    const int c = ct * 128 + wc * 64 + j * 16 + l15;
                    if (c < C_NUM) {
                        const float4 wv = *(const float4*)(W + (size_t)c * A_DIM + a0);
                        const f32x4 u = acc[i][j];
                        qp[ct][j] += u[0] * (wv.x - wl_e.x) + u[1] * (wv.y - wl_e.y)
                                   + u[2] * (wv.z - wl_e.z) + u[3] * (wv.w - wl_e.w);
                    }
                }
            }
        }
    }

    // reduce over 4 g-groups (same c, different a rows) within each wave,
    // then combine the two wa-waves through LDS and store (no global atomics)
    float vout[3][4];
#pragma unroll
    for (int ct = 0; ct < 3; ct++)
#pragma unroll
        for (int j = 0; j < 4; j++) {
            float v = qp[ct][j];
            v += __shfl_xor(v, 16);
            v += __shfl_xor(v, 32);
            vout[ct][j] = v;
        }
    if (g == 0 && wa == 1) {
#pragma unroll
        for (int ct = 0; ct < 3; ct++)
#pragma unroll
            for (int j = 0; j < 4; j++)
                qred[ct * 128 + wc * 64 + j * 16 + l15] = vout[ct][j];
    }
    __syncthreads();
    if (g == 0 && wa == 0) {
        float* dst = q2buf + ((size_t)bb * N_NUM + n) * C_NUM;
#pragma unroll
        for (int ct = 0; ct < 3; ct++)
#pragma unroll
            for (int j = 0; j < 4; j++) {
                const int c = ct * 128 + wc * 64 + j * 16 + l15;
                if (c < C_NUM) dst[c] = vout[ct][j] + qred[c];
            }
    }
}

// aug[c] = ys + 0.5*Lam*q2 + Lam*(w_c - w_l).dm ; nll = logsumexp - aug[l]
__global__ __launch_bounds__(256) void losskern(
    const float* __restrict__ W,
    const float* __restrict__ ys,
    const int*   __restrict__ labels,
    const float* __restrict__ lambda_p,
    const float* __restrict__ mean_s,
    const float* __restrict__ mean_t,
    const float* __restrict__ q2buf,
    float*       __restrict__ out)
{
    const int n = blockIdx.x;
    const int tid = threadIdx.x;
    const int lane = tid & 63;
    const int w = tid >> 6;
    const int l = labels[n];
    const float Lam = *lambda_p;

    // representative n for this label (q2 depends on l only)
    int rep = n;
    for (int m = 0; m < n; m++) if (labels[m] == l) { rep = m; break; }

    __shared__ float aug[C_NUM];
    __shared__ float red[256];

    // per-lane 8-element slice of the A dimension
    const int a0 = lane * 8;
    const float* Wl = W + (size_t)l * A_DIM;
    const float4 wl0 = *(const float4*)(Wl + a0);
    const float4 wl1 = *(const float4*)(Wl + a0 + 4);
    const float4 mt0 = *(const float4*)(mean_t + (size_t)l * A_DIM + a0);
    const float4 mt1 = *(const float4*)(mean_t + (size_t)l * A_DIM + a0 + 4);
    const float4 ms0 = *(const float4*)(mean_s + (size_t)l * A_DIM + a0);
    const float4 ms1 = *(const float4*)(mean_s + (size_t)l * A_DIM + a0 + 4);
    const float dm0 = mt0.x - ms0.x, dm1 = mt0.y - ms0.y, dm2 = mt0.z - ms0.z, dm3 = mt0.w - ms0.w;
    const float dm4 = mt1.x - ms1.x, dm5 = mt1.y - ms1.y, dm6 = mt1.z - ms1.z, dm7 = mt1.w - ms1.w;
    const float wldm = wl0.x*dm0 + wl0.y*dm1 + wl0.z*dm2 + wl0.w*dm3
                     + wl1.x*dm4 + wl1.y*dm5 + wl1.z*dm6 + wl1.w*dm7;

    // wave-per-row dot products; the 8 q2buf b-slices ride the same 64-lane
    // reduction (lanes 0..7 each add 0.5*q2_slice; aug = ys + Lam*total)
    for (int c = w; c < C_NUM; c += 4) {
        const float* Wc = W + (size_t)c * A_DIM;
        const float4 w0 = *(const float4*)(Wc + a0);
        const float4 w1 = *(const float4*)(Wc + a0 + 4);
        float d = w0.x*dm0 + w0.y*dm1 + w0.z*dm2 + w0.w*dm3
                + w1.x*dm4 + w1.y*dm5 + w1.z*dm6 + w1.w*dm7 - wldm;
        if (lane < NBB)
            d += 0.5f * q2buf[((size_t)lane * N_NUM + rep) * C_NUM + c];
        d += __shfl_xor(d, 1);
        d += __shfl_xor(d, 2);
        d += __shfl_xor(d, 4);
        d += __shfl_xor(d, 8);
        d += __shfl_xor(d, 16);
        d += __shfl_xor(d, 32);
        if (lane == 0)
            aug[c] = ys[(size_t)n * C_NUM + c] + Lam * d;
    }
    __syncthreads();

    float m = -INFINITY;
    for (int c = tid; c < C_NUM; c += 256) m = fmaxf(m, aug[c]);
    red[tid] = m;
    __syncthreads();
    for (int s = 128; s > 0; s >>= 1) {
        if (tid < s) red[tid] = fmaxf(red[tid], red[tid + s]);
        __syncthreads();
    }
    m = red[0];
    __syncthreads();

    float se = 0.f;
    for (int c = tid; c < C_NUM; c += 256) se += expf(aug[c] - m);
    red[tid] = se;
    __syncthreads();
    for (int s = 128; s > 0; s >>= 1) {
        if (tid < s) red[tid] += red[tid + s];
        __syncthreads();
    }
    if (tid == 0) {
        const float logZ = m + logf(red[0]);
        atomicAdd(out, (logZ - aug[l]) * (1.f / (float)N_NUM));
    }
}

extern "C" void kernel_launch(void* const* d_in, const int* in_sizes, int n_in,
                              void* d_out, int out_size, void* d_ws, size_t ws_size,
                              hipStream_t stream) {
    const float* W      = (const float*)d_in[0];
    // d_in[1] = features_source: unused by the reference.
    const float* ys     = (const float*)d_in[2];
    const int*   labels = (const int*)d_in[3];
    const float* lam    = (const float*)d_in[4];
    const float* means  = (const float*)d_in[5];
    const float* meant  = (const float*)d_in[6];
    const float* cov    = (const float*)d_in[7];
    float* out = (float*)d_out;
    float* q2buf = (float*)d_ws;   // NBB*N*C floats = 1.41 MB, plain-stored

    // out must start at 0 for the final atomicAdd; q2buf needs NO memset
    // (every read slice is written by its bb-block before losskern runs).
    hipMemsetAsync(out, 0, sizeof(float), stream);

    qkern<<<dim3(NBB, N_NUM), 256, 0, stream>>>(W, labels, cov, q2buf);
    losskern<<<N_NUM, 256, 0, stream>>>(W, ys, labels, lam, means, meant, q2buf, out);
}